// Round 6
// baseline (16947.752 us; speedup 1.0000x reference)
//
#include <hip/hip_runtime.h>
#include <hip/hip_bf16.h>

typedef unsigned short u16;
typedef unsigned int u32;
typedef unsigned long long u64;
typedef __attribute__((ext_vector_type(8))) short short8;
typedef __attribute__((ext_vector_type(4))) short short4v;
typedef __attribute__((ext_vector_type(4))) float float4v;
typedef __attribute__((ext_vector_type(2))) unsigned int uint2v;
typedef __attribute__((ext_vector_type(4))) unsigned int uint4v;

#define Bsz 64
#define Tsz 512
#define Fsz 128
#define Usz 512
#define Gsz 2048
#define Msz 32768
#define OUTW 1152
#define BINW 640
#define NWG 16        // scan workgroups (barrier participants)
#define FLSTR 32      // flag stride in u32 (128B lines)

__device__ __forceinline__ u16 f2b(float f) {
  u32 u = __float_as_uint(f);
  u32 r = (u + 0x7fffu + ((u >> 16) & 1u)) >> 16;
  return (u16)r;
}
__device__ __forceinline__ float b2f(u16 h) {
  return __uint_as_float(((u32)h) << 16);
}
__device__ __forceinline__ float sigm(float x) { return 1.f / (1.f + __expf(-x)); }
__device__ __forceinline__ float tanhfast(float x) { return 2.f / (1.f + __expf(-2.f * x)) - 1.f; }

// ---------------- weight transpose + bf16 convert: dst[n][k] = bf16(src[k][n]) ----
__global__ void k_wt(const float* __restrict__ src, u16* __restrict__ dst, int K, int N) {
  __shared__ float t[32][33];
  int k0 = blockIdx.y << 5, n0 = blockIdx.x << 5;
  int tid = threadIdx.x;
  int r = tid >> 3, c = (tid & 7) << 2;
  float4v v = *(const float4v*)(src + (size_t)(k0 + r) * N + n0 + c);
  t[r][c + 0] = v[0]; t[r][c + 1] = v[1]; t[r][c + 2] = v[2]; t[r][c + 3] = v[3];
  __syncthreads();
  short4v o;
  o[0] = (short)f2b(t[c + 0][r]);
  o[1] = (short)f2b(t[c + 1][r]);
  o[2] = (short)f2b(t[c + 2][r]);
  o[3] = (short)f2b(t[c + 3][r]);
  *(short4v*)(dst + (size_t)(n0 + r) * K + k0 + c) = o;
}

// ---------------- copy x into d_out cols [0,128) and bin (bf16) cols [0,128) ------
__global__ void k_cvx(const float* __restrict__ x, float* __restrict__ dout, u16* __restrict__ bin) {
  int id = blockIdx.x * 256 + threadIdx.x;
  int row = id >> 5, c = (id & 31) << 2;
  float4v v = *(const float4v*)(x + (size_t)row * Fsz + c);
  *(float4v*)(dout + (size_t)row * OUTW + c) = v;
  short4v o;
  o[0] = (short)f2b(v[0]); o[1] = (short)f2b(v[1]);
  o[2] = (short)f2b(v[2]); o[3] = (short)f2b(v[3]);
  *(short4v*)(bin + (size_t)row * BINW + c) = o;
}

// ---------------- bf16 MFMA GEMM: C = A * Bt^T + bias ------------------------------
// Logical row mlog = t*64 + b.
// APERM: A physical row = b*512 + t; else physical = mlog.
// CPERM: C -> xw2 layout [t][u][b][g], n = g*512+u; else C[mlog][n].
template <int APERM, int CPERM>
__launch_bounds__(256)
__global__ void k_gemm(const u16* __restrict__ A, int lda,
                       const u16* __restrict__ Bt, int K, int N,
                       const float* __restrict__ bias,
                       u16* __restrict__ C) {
  __shared__ u16 Al[128][40];
  __shared__ u16 Bl[64][40];
  int tid = threadIdx.x;
  int lane = tid & 63, wid = tid >> 6;
  int n0 = blockIdx.x << 6;
  size_t m0 = (size_t)blockIdx.y << 7;
  int mr = lane & 15, ko = (lane >> 4) << 3;
  float4v acc[2][4];
#pragma unroll
  for (int i = 0; i < 2; ++i)
#pragma unroll
    for (int j = 0; j < 4; ++j) acc[i][j] = (float4v){0.f, 0.f, 0.f, 0.f};

  for (int k0 = 0; k0 < K; k0 += 32) {
#pragma unroll
    for (int i = 0; i < 2; ++i) {
      int id = tid + (i << 8);
      int row = id >> 2, kc = (id & 3) << 3;
      int mlog = (int)m0 + row;
      size_t rp = APERM ? ((size_t)(mlog & 63) << 9) + (mlog >> 6) : (size_t)mlog;
      *(short8*)&Al[row][kc] = *(const short8*)(A + rp * (size_t)lda + k0 + kc);
    }
    {
      int row = tid >> 2, kc = (tid & 3) << 3;
      *(short8*)&Bl[row][kc] = *(const short8*)(Bt + (size_t)(n0 + row) * K + k0 + kc);
    }
    __syncthreads();
    short8 af0 = *(short8*)&Al[(wid << 5) + mr][ko];
    short8 af1 = *(short8*)&Al[(wid << 5) + 16 + mr][ko];
    short8 bf0 = *(short8*)&Bl[mr][ko];
    short8 bf1 = *(short8*)&Bl[16 + mr][ko];
    short8 bf2 = *(short8*)&Bl[32 + mr][ko];
    short8 bf3 = *(short8*)&Bl[48 + mr][ko];
    acc[0][0] = __builtin_amdgcn_mfma_f32_16x16x32_bf16(af0, bf0, acc[0][0], 0, 0, 0);
    acc[0][1] = __builtin_amdgcn_mfma_f32_16x16x32_bf16(af0, bf1, acc[0][1], 0, 0, 0);
    acc[0][2] = __builtin_amdgcn_mfma_f32_16x16x32_bf16(af0, bf2, acc[0][2], 0, 0, 0);
    acc[0][3] = __builtin_amdgcn_mfma_f32_16x16x32_bf16(af0, bf3, acc[0][3], 0, 0, 0);
    acc[1][0] = __builtin_amdgcn_mfma_f32_16x16x32_bf16(af1, bf0, acc[1][0], 0, 0, 0);
    acc[1][1] = __builtin_amdgcn_mfma_f32_16x16x32_bf16(af1, bf1, acc[1][1], 0, 0, 0);
    acc[1][2] = __builtin_amdgcn_mfma_f32_16x16x32_bf16(af1, bf2, acc[1][2], 0, 0, 0);
    acc[1][3] = __builtin_amdgcn_mfma_f32_16x16x32_bf16(af1, bf3, acc[1][3], 0, 0, 0);
    __syncthreads();
  }
  int rbase = (lane >> 4) << 2;
#pragma unroll
  for (int mt = 0; mt < 2; ++mt)
#pragma unroll
    for (int nt = 0; nt < 4; ++nt) {
      int n = n0 + (nt << 4) + mr;
      float bv = bias[n];
#pragma unroll
      for (int r = 0; r < 4; ++r) {
        int mlog = (int)m0 + (wid << 5) + (mt << 4) + rbase + r;
        float val = acc[mt][nt][r] + bv;
        if (CPERM) {
          int b = mlog & 63, tt = mlog >> 6;
          int u = n & 511, g = n >> 9;
          C[((((size_t)tt * 512 + u) * 64 + b) << 2) + g] = f2b(val);
        } else {
          C[(size_t)mlog * N + n] = f2b(val);
        }
      }
    }
}

// ---------------- zero flags ------------------------------------------------------
__global__ void k_zero(u32* __restrict__ p, int n32) {
  int id = blockIdx.x * 256 + threadIdx.x;
  for (int i = id; i < n32; i += gridDim.x * 256) p[i] = 0u;
}

// ---------------- persistent LSTM scan ---------------------------------------------
// r4 skeleton; coherence is now TARGETED instead of global:
//  - h published via agent-scope relaxed u64 atomic stores (device-visible data)
//  - flag via agent-scope RELEASE store (orders stragglers; cheap, few dirty lines)
//  - poll via agent-scope relaxed loads, **no threadfence invalidate**
//  - h staged via agent-scope relaxed u64 atomic loads -> regs -> ds_write
//    (bypasses stale L1/L2 by memory-model contract; local L2/xw prefetch stays warm)
__launch_bounds__(256, 1)
__global__ void k_scan(const u16* __restrict__ xw2,   // [t][u][b][g] bf16
                       const u16* __restrict__ Ut,    // [g*512+u][k] bf16
                       u16* __restrict__ hn,          // ping-pong 2 x [64][512] bf16
                       u16* __restrict__ hseq,        // [t][b][u] bf16
                       u32* __restrict__ bar) {
  __shared__ u16 hl[32768];   // 64 KB staged h chunks (chunk c = 64 lanes x 16B)
  __shared__ u16 hout[2048];  // 4 KB transpose buffer [64 b][32 u] swizzled
  int wg = blockIdx.x;
  int tid = threadIdx.x;
  int lane = tid & 63, wid = tid >> 6;
  int mr = lane & 15, cg = lane >> 4;
  int gate = mr & 3, du = mr >> 2;
  int u0 = (wg << 5) + (wid << 3);

  // U^T fragments, constant across steps: 128 VGPRs
  short8 af[2][16];
#pragma unroll
  for (int mt = 0; mt < 2; ++mt) {
    size_t urow = (size_t)(gate * Usz + u0 + (mt << 2) + du) * Usz;
#pragma unroll
    for (int kk = 0; kk < 16; ++kk)
      af[mt][kk] = *(const short8*)(Ut + urow + (kk << 5) + (cg << 3));
  }

  float cst[2][4];
#pragma unroll
  for (int mt = 0; mt < 2; ++mt)
#pragma unroll
    for (int nt = 0; nt < 4; ++nt) cst[mt][nt] = 0.f;

  short4v xwc[2][4], xwn[2][4];
#pragma unroll
  for (int mt = 0; mt < 2; ++mt)
#pragma unroll
    for (int nt = 0; nt < 4; ++nt)
      xwc[mt][nt] = *(const short4v*)(xw2 + ((((size_t)0 * 512 + u0 + (mt << 2) + cg) * 64
                                             + (nt << 4) + mr) << 2));

  for (int t = 0; t < Tsz; ++t) {
    const u16* rbuf = hn + ((t & 1) ? 32768 : 0);   // written at step t-1
    u16* wbuf = hn + ((t & 1) ? 0 : 32768);

    // acc = xw(t)
    float4v acc[2][4];
#pragma unroll
    for (int mt = 0; mt < 2; ++mt)
#pragma unroll
      for (int nt = 0; nt < 4; ++nt)
        acc[mt][nt] = (float4v){b2f((u16)xwc[mt][nt][0]), b2f((u16)xwc[mt][nt][1]),
                                b2f((u16)xwc[mt][nt][2]), b2f((u16)xwc[mt][nt][3])};

    // prefetch xw(t+1) — rides out poll/stage/MFMA; lines stay warm (no L2 inv)
    if (t + 1 < Tsz) {
#pragma unroll
      for (int mt = 0; mt < 2; ++mt)
#pragma unroll
        for (int nt = 0; nt < 4; ++nt)
          xwn[mt][nt] = *(const short4v*)(xw2 + ((((size_t)(t + 1) * 512 + u0 + (mt << 2) + cg) * 64
                                                 + (nt << 4) + mr) << 2));
    }

    if (t > 0) {
      // ---- parallel flag poll: all WGs published h[t-1]; NO cache invalidate ----
      if (wid == 0) {
        u32 tgt = (u32)t;
        for (;;) {
          u32 v = (lane < NWG)
                    ? __hip_atomic_load(bar + lane * FLSTR, __ATOMIC_RELAXED, __HIP_MEMORY_SCOPE_AGENT)
                    : 0xFFFFFFFFu;
          if (__all(v >= tgt)) break;
          __builtin_amdgcn_s_sleep(1);
        }
      }
      __syncthreads();

      // ---- stage h[t-1]: coherent agent-scope loads -> regs -> LDS chunks ----
      {
        const char* hsrc = (const char*)rbuf;
        u64 hv0[16], hv1[16];
#pragma unroll
        for (int j = 0; j < 16; ++j) {
          int c = (wid << 4) + j;               // chunk = kk*4 + nt
          const char* src = hsrc + ((((c & 3) << 4) + mr) << 10) + ((c >> 2) << 6) + (cg << 4);
          hv0[j] = __hip_atomic_load((const u64*)src, __ATOMIC_RELAXED, __HIP_MEMORY_SCOPE_AGENT);
          hv1[j] = __hip_atomic_load((const u64*)(src + 8), __ATOMIC_RELAXED, __HIP_MEMORY_SCOPE_AGENT);
        }
#pragma unroll
        for (int j = 0; j < 16; ++j) {
          int c = (wid << 4) + j;
          char* dst = (char*)hl + (c << 10) + (lane << 4);
          *(u64*)dst = hv0[j];
          *(u64*)(dst + 8) = hv1[j];
        }
      }
      __syncthreads();  // LDS writes visible to all waves

      // ---- MFMA: 64 linear ds_read_b128 + 128 MFMA per wave ----
#pragma unroll
      for (int kk = 0; kk < 16; ++kk) {
        short8 bfr[4];
#pragma unroll
        for (int nt = 0; nt < 4; ++nt)
          bfr[nt] = *(const short8*)(hl + ((((kk << 2) + nt) << 9) + (lane << 3)));
#pragma unroll
        for (int mt = 0; mt < 2; ++mt)
#pragma unroll
          for (int nt = 0; nt < 4; ++nt)
            acc[mt][nt] = __builtin_amdgcn_mfma_f32_16x16x32_bf16(af[mt][kk], bfr[nt], acc[mt][nt], 0, 0, 0);
      }
    }

    // ---- gates (register-only) ----
    u16 hb[2][4];
#pragma unroll
    for (int mt = 0; mt < 2; ++mt)
#pragma unroll
      for (int nt = 0; nt < 4; ++nt) {
        float zi = acc[mt][nt][0], zf = acc[mt][nt][1];
        float zg = acc[mt][nt][2], zo = acc[mt][nt][3];
        float c = sigm(zf) * cst[mt][nt] + sigm(zi) * tanhfast(zg);
        cst[mt][nt] = c;
        hb[mt][nt] = f2b(sigm(zo) * tanhfast(c));
      }

    // ---- h -> LDS transpose (swizzled [b][u_local]) ----
#pragma unroll
    for (int mt = 0; mt < 2; ++mt)
#pragma unroll
      for (int nt = 0; nt < 4; ++nt) {
        int b = (nt << 4) + mr;
        int ul = (wid << 3) + (mt << 2) + cg;
        *(u16*)((char*)hout + (b << 6) + ((ul << 1) ^ ((b & 7) << 3))) = hb[mt][nt];
      }
    __syncthreads();

    // ---- coalesced hn publish: agent-scope u64 stores (device-visible data) ----
    uint4v val;
    {
      int b = tid >> 2, q = tid & 3, s = (b & 7) << 3;
      const char* hrow = (const char*)hout + (b << 6);
      uint2v A0 = *(const uint2v*)(hrow + (((q << 4) | 0) ^ s));
      uint2v A1 = *(const uint2v*)(hrow + (((q << 4) | 8) ^ s));
      val[0] = A0[0]; val[1] = A0[1]; val[2] = A1[0]; val[3] = A1[1];
      char* dsthn = (char*)wbuf + (b << 10) + (wg << 6) + (q << 4);
      u64 lo = (u64)val[0] | ((u64)val[1] << 32);
      u64 hi = (u64)val[2] | ((u64)val[3] << 32);
      __hip_atomic_store((u64*)dsthn, lo, __ATOMIC_RELAXED, __HIP_MEMORY_SCOPE_AGENT);
      __hip_atomic_store((u64*)(dsthn + 8), hi, __ATOMIC_RELAXED, __HIP_MEMORY_SCOPE_AGENT);
    }
    __syncthreads();  // all waves' stores acked (vmcnt0 before s_barrier)

    if (tid == 0)
      __hip_atomic_store(bar + wg * FLSTR, (u32)(t + 1), __ATOMIC_RELEASE, __HIP_MEMORY_SCOPE_AGENT);

    // streaming hseq store: off the critical path (drains during next poll)
    {
      int b = tid >> 2, q = tid & 3;
      *(uint4v*)((char*)hseq + ((size_t)t << 16) + (b << 10) + (wg << 6) + (q << 4)) = val;
    }

    if (t + 1 < Tsz) {
#pragma unroll
      for (int mt = 0; mt < 2; ++mt)
#pragma unroll
        for (int nt = 0; nt < 4; ++nt) xwc[mt][nt] = xwn[mt][nt];
    }
  }
}

// ---------------- row LayerNorm (bf16 in -> bf16 out), row-order agnostic ----------
__launch_bounds__(256)
__global__ void k_ln(const u16* __restrict__ in, const float* __restrict__ g,
                     const float* __restrict__ be, u16* __restrict__ out) {
  int lane = threadIdx.x & 63, wid = threadIdx.x >> 6;
  size_t row = (size_t)blockIdx.x * 4 + wid;
  short8 v = *(const short8*)(in + row * Usz + (lane << 3));
  float f[8];
  float s = 0.f, q = 0.f;
#pragma unroll
  for (int j = 0; j < 8; ++j) { f[j] = b2f((u16)v[j]); s += f[j]; q += f[j] * f[j]; }
#pragma unroll
  for (int o = 32; o > 0; o >>= 1) { s += __shfl_xor(s, o); q += __shfl_xor(q, o); }
  float mean = s * (1.f / 512.f);
  float var = q * (1.f / 512.f) - mean * mean;
  float rs = rsqrtf(var + 1e-3f);
  float4v g0 = *(const float4v*)(g + (lane << 3));
  float4v g1 = *(const float4v*)(g + (lane << 3) + 4);
  float4v e0 = *(const float4v*)(be + (lane << 3));
  float4v e1 = *(const float4v*)(be + (lane << 3) + 4);
  short8 o8;
#pragma unroll
  for (int j = 0; j < 8; ++j) {
    float gg = (j < 4) ? g0[j] : g1[j - 4];
    float ee = (j < 4) ? e0[j] : e1[j - 4];
    o8[j] = (short)f2b((f[j] - mean) * rs * gg + ee);
  }
  *(short8*)(out + row * Usz + (lane << 3)) = o8;
}

// ---------------- LayerNorm + highway fused; rows are [t][b], outputs go to [b][t] --
__launch_bounds__(256)
__global__ void k_lnhw(const u16* __restrict__ hs, const float* __restrict__ g,
                       const float* __restrict__ be, const u16* __restrict__ txr,
                       const u16* __restrict__ ob, float* __restrict__ dout,
                       int dcol, u16* __restrict__ bin) {
  int lane = threadIdx.x & 63, wid = threadIdx.x >> 6;
  size_t row = (size_t)blockIdx.x * 4 + wid;       // physical row = t*64 + b
  short8 v = *(const short8*)(hs + row * Usz + (lane << 3));
  float f[8];
  float s = 0.f, q = 0.f;
#pragma unroll
  for (int j = 0; j < 8; ++j) { f[j] = b2f((u16)v[j]); s += f[j]; q += f[j] * f[j]; }
#pragma unroll
  for (int o = 32; o > 0; o >>= 1) { s += __shfl_xor(s, o); q += __shfl_xor(q, o); }
  float mean = s * (1.f / 512.f);
  float var = q * (1.f / 512.f) - mean * mean;
  float rs = rsqrtf(var + 1e-3f);
  float4v g0 = *(const float4v*)(g + (lane << 3));
  float4v g1 = *(const float4v*)(g + (lane << 3) + 4);
  float4v e0 = *(const float4v*)(be + (lane << 3));
  float4v e1 = *(const float4v*)(be + (lane << 3) + 4);
  short8 tv = *(const short8*)(txr + row * Usz + (lane << 3));
  short8 ov = *(const short8*)(ob + row * Usz + (lane << 3));
  float hwv[8];
#pragma unroll
  for (int j = 0; j < 8; ++j) {
    float gg = (j < 4) ? g0[j] : g1[j - 4];
    float ee = (j < 4) ? e0[j] : e1[j - 4];
    float hx = (f[j] - mean) * rs * gg + ee;
    float tx = sigm(b2f((u16)tv[j]));
    float o_ = b2f((u16)ov[j]);
    hwv[j] = hx * tx + (1.f - tx) * o_;
  }
  size_t orow = ((row & 63) << 9) + (row >> 6);    // b*512 + t
  float4v w0 = {hwv[0], hwv[1], hwv[2], hwv[3]};
  float4v w1 = {hwv[4], hwv[5], hwv[6], hwv[7]};
  *(float4v*)(dout + orow * OUTW + dcol + (lane << 3)) = w0;
  *(float4v*)(dout + orow * OUTW + dcol + (lane << 3) + 4) = w1;
  if (bin) {
    short8 hb;
#pragma unroll
    for (int j = 0; j < 8; ++j) hb[j] = (short)f2b(hwv[j]);
    *(short8*)(bin + orow * BINW + 128 + (lane << 3)) = hb;
  }
}

// ====================================================================================
extern "C" void kernel_launch(void* const* d_in, const int* in_sizes, int n_in,
                              void* d_out, int out_size, void* d_ws, size_t ws_size,
                              hipStream_t stream) {
  (void)in_sizes; (void)n_in; (void)out_size; (void)ws_size;
  const float* x = (const float*)d_in[0];
  const float* W[4]  = {(const float*)d_in[1],  (const float*)d_in[6],
                        (const float*)d_in[11], (const float*)d_in[16]};
  const float* U[4]  = {(const float*)d_in[2],  (const float*)d_in[7],
                        (const float*)d_in[12], (const float*)d_in[17]};
  const float* bb_[4] = {(const float*)d_in[3],  (const float*)d_in[8],
                        (const float*)d_in[13], (const float*)d_in[18]};
  const float* gg_[4] = {(const float*)d_in[4],  (const float*)d_in[9],
                        (const float*)d_in[14], (const float*)d_in[19]};
  const float* be_[4] = {(const float*)d_in[5],  (const float*)d_in[10],
                        (const float*)d_in[15], (const float*)d_in[20]};
  const float* Wtr[2] = {(const float*)d_in[21], (const float*)d_in[23]};
  const float* btr[2] = {(const float*)d_in[22], (const float*)d_in[24]};

  char* ws = (char*)d_ws;
  size_t off = 0;
  u16* xwb  = (u16*)(ws + off); off += (size_t)Msz * Gsz * 2;
  u16* hseq = (u16*)(ws + off); off += (size_t)Msz * Usz * 2;   // [t][b][u]
  u16* mid  = (u16*)(ws + off); off += (size_t)Msz * Usz * 2;   // [t][b][u]
  u16* bin  = (u16*)(ws + off); off += (size_t)Msz * BINW * 2;  // [b][t][640]
  const int KIN[4] = {128, 512, 640, 512};
  u16* Wtb[4];
  for (int i = 0; i < 4; ++i) { Wtb[i] = (u16*)(ws + off); off += (size_t)Gsz * KIN[i] * 2; }
  u16* Utb[4];
  for (int i = 0; i < 4; ++i) { Utb[i] = (u16*)(ws + off); off += (size_t)Gsz * Usz * 2; }
  u16* Wtrb[2];
  for (int i = 0; i < 2; ++i) { Wtrb[i] = (u16*)(ws + off); off += (size_t)Usz * Usz * 2; }
  u16* hn = (u16*)(ws + off); off += 2 * (size_t)Bsz * Usz * 2; // ping-pong
  u32* bar = (u32*)(ws + off); off += 4096;                     // 1024 u32
  float* dout = (float*)d_out;

  for (int i = 0; i < 4; ++i)
    k_wt<<<dim3(Gsz / 32, KIN[i] / 32), 256, 0, stream>>>(W[i], Wtb[i], KIN[i], Gsz);
  for (int i = 0; i < 4; ++i)
    k_wt<<<dim3(Gsz / 32, Usz / 32), 256, 0, stream>>>(U[i], Utb[i], Usz, Gsz);
  for (int i = 0; i < 2; ++i)
    k_wt<<<dim3(Usz / 32, Usz / 32), 256, 0, stream>>>(Wtr[i], Wtrb[i], Usz, Usz);

  k_cvx<<<(Msz * 32) / 256, 256, 0, stream>>>(x, dout, bin);

  for (int blk = 0; blk < 2; ++blk) {
    int l0 = blk * 2, l1 = blk * 2 + 1;
    // layer 0: xW GEMM (A from bin [b][t], C -> xw2) -> scan -> LN
    k_gemm<1, 1><<<dim3(Gsz / 64, Msz / 128), 256, 0, stream>>>(bin, BINW, Wtb[l0], KIN[l0], Gsz, bb_[l0], xwb);
    k_zero<<<1, 256, 0, stream>>>(bar, 1024);
    k_scan<<<NWG, 256, 0, stream>>>(xwb, Utb[l0], hn, hseq, bar);
    k_ln<<<Msz / 4, 256, 0, stream>>>(hseq, gg_[l0], be_[l0], mid);
    // layer 1: xW GEMM (A rows [t][b], C -> xw2) -> scan
    k_gemm<0, 1><<<dim3(Gsz / 64, Msz / 128), 256, 0, stream>>>(mid, Usz, Wtb[l1], Usz, Gsz, bb_[l1], xwb);
    k_zero<<<1, 256, 0, stream>>>(bar, 1024);
    k_scan<<<NWG, 256, 0, stream>>>(xwb, Utb[l1], hn, hseq, bar);
    // highway transform gate: Tx_raw = mid @ Wtr + btr (standard C, rows [t][b])
    k_gemm<0, 0><<<dim3(Usz / 64, Msz / 128), 256, 0, stream>>>(mid, Usz, Wtrb[blk], Usz, Usz, btr[blk], xwb);
    // LN + highway: fp32 out slice (+ bf16 into bin for block-1 input)
    k_lnhw<<<Msz / 4, 256, 0, stream>>>(hseq, gg_[l1], be_[l1], xwb, mid, dout,
                                        blk == 0 ? 128 : 640, blk == 0 ? bin : (u16*)nullptr);
  }
}

// Round 7
// 12022.474 us; speedup vs baseline: 1.4097x; 1.4097x over previous
//
#include <hip/hip_runtime.h>
#include <hip/hip_bf16.h>

typedef unsigned short u16;
typedef unsigned int u32;
typedef unsigned long long u64;
typedef __attribute__((ext_vector_type(8))) short short8;
typedef __attribute__((ext_vector_type(4))) short short4v;
typedef __attribute__((ext_vector_type(4))) float float4v;
typedef __attribute__((ext_vector_type(2))) float float2v;
typedef __attribute__((ext_vector_type(2))) unsigned int uint2v;
typedef __attribute__((ext_vector_type(4))) unsigned int uint4v;

#define Bsz 64
#define Tsz 512
#define Fsz 128
#define Usz 512
#define Gsz 2048
#define Msz 32768
#define OUTW 1152
#define BINW 640
#define NWG 16        // WGs per scan group
#define FLSTR 32      // flag stride in u32 (128B lines)

__device__ __forceinline__ u16 f2b(float f) {
  u32 u = __float_as_uint(f);
  u32 r = (u + 0x7fffu + ((u >> 16) & 1u)) >> 16;
  return (u16)r;
}
__device__ __forceinline__ float b2f(u16 h) {
  return __uint_as_float(((u32)h) << 16);
}
__device__ __forceinline__ float sigm(float x) { return 1.f / (1.f + __expf(-x)); }
__device__ __forceinline__ float tanhfast(float x) { return 2.f / (1.f + __expf(-2.f * x)) - 1.f; }

// ---------------- weight transpose + bf16 (+optional row-scale by scale[k]) --------
__global__ void k_wt(const float* __restrict__ src, u16* __restrict__ dst, int K, int N,
                     const float* __restrict__ scale) {
  __shared__ float t[32][33];
  int k0 = blockIdx.y << 5, n0 = blockIdx.x << 5;
  int tid = threadIdx.x;
  int r = tid >> 3, c = (tid & 7) << 2;
  float4v v = *(const float4v*)(src + (size_t)(k0 + r) * N + n0 + c);
  float s = scale ? scale[k0 + r] : 1.f;
  t[r][c + 0] = v[0] * s; t[r][c + 1] = v[1] * s;
  t[r][c + 2] = v[2] * s; t[r][c + 3] = v[3] * s;
  __syncthreads();
  short4v o;
  o[0] = (short)f2b(t[c + 0][r]);
  o[1] = (short)f2b(t[c + 1][r]);
  o[2] = (short)f2b(t[c + 2][r]);
  o[3] = (short)f2b(t[c + 3][r]);
  *(short4v*)(dst + (size_t)(n0 + r) * K + k0 + c) = o;
}

// ---------------- p[n] = sum_k W[k][n]*g[k];  q[n] = sum_k W[k][n]*be[k] + b1[n] ----
__global__ void k_pq(const float* __restrict__ W, const float* __restrict__ g,
                     const float* __restrict__ be, const float* __restrict__ b1,
                     float* __restrict__ p, float* __restrict__ q) {
  int n = blockIdx.x * 256 + threadIdx.x;   // 2048
  float sp = 0.f, sq = 0.f;
  for (int k = 0; k < Usz; ++k) {
    float w = W[(size_t)k * Gsz + n];
    sp += w * g[k]; sq += w * be[k];
  }
  p[n] = sp; q[n] = sq + b1[n];
}

// ---------------- copy x into d_out cols [0,128) and bin (bf16) cols [0,128) ------
__global__ void k_cvx(const float* __restrict__ x, float* __restrict__ dout, u16* __restrict__ bin) {
  int id = blockIdx.x * 256 + threadIdx.x;
  int row = id >> 5, c = (id & 31) << 2;
  float4v v = *(const float4v*)(x + (size_t)row * Fsz + c);
  *(float4v*)(dout + (size_t)row * OUTW + c) = v;
  short4v o;
  o[0] = (short)f2b(v[0]); o[1] = (short)f2b(v[1]);
  o[2] = (short)f2b(v[2]); o[3] = (short)f2b(v[3]);
  *(short4v*)(bin + (size_t)row * BINW + c) = o;
}

// ---------------- bf16 MFMA GEMM (r4-verbatim) --------------------------------------
template <int APERM, int CPERM>
__launch_bounds__(256)
__global__ void k_gemm(const u16* __restrict__ A, int lda,
                       const u16* __restrict__ Bt, int K, int N,
                       const float* __restrict__ bias,
                       u16* __restrict__ C) {
  __shared__ u16 Al[128][40];
  __shared__ u16 Bl[64][40];
  int tid = threadIdx.x;
  int lane = tid & 63, wid = tid >> 6;
  int n0 = blockIdx.x << 6;
  size_t m0 = (size_t)blockIdx.y << 7;
  int mr = lane & 15, ko = (lane >> 4) << 3;
  float4v acc[2][4];
#pragma unroll
  for (int i = 0; i < 2; ++i)
#pragma unroll
    for (int j = 0; j < 4; ++j) acc[i][j] = (float4v){0.f, 0.f, 0.f, 0.f};

  for (int k0 = 0; k0 < K; k0 += 32) {
#pragma unroll
    for (int i = 0; i < 2; ++i) {
      int id = tid + (i << 8);
      int row = id >> 2, kc = (id & 3) << 3;
      int mlog = (int)m0 + row;
      size_t rp = APERM ? ((size_t)(mlog & 63) << 9) + (mlog >> 6) : (size_t)mlog;
      *(short8*)&Al[row][kc] = *(const short8*)(A + rp * (size_t)lda + k0 + kc);
    }
    {
      int row = tid >> 2, kc = (tid & 3) << 3;
      *(short8*)&Bl[row][kc] = *(const short8*)(Bt + (size_t)(n0 + row) * K + k0 + kc);
    }
    __syncthreads();
    short8 af0 = *(short8*)&Al[(wid << 5) + mr][ko];
    short8 af1 = *(short8*)&Al[(wid << 5) + 16 + mr][ko];
    short8 bf0 = *(short8*)&Bl[mr][ko];
    short8 bf1 = *(short8*)&Bl[16 + mr][ko];
    short8 bf2 = *(short8*)&Bl[32 + mr][ko];
    short8 bf3 = *(short8*)&Bl[48 + mr][ko];
    acc[0][0] = __builtin_amdgcn_mfma_f32_16x16x32_bf16(af0, bf0, acc[0][0], 0, 0, 0);
    acc[0][1] = __builtin_amdgcn_mfma_f32_16x16x32_bf16(af0, bf1, acc[0][1], 0, 0, 0);
    acc[0][2] = __builtin_amdgcn_mfma_f32_16x16x32_bf16(af0, bf2, acc[0][2], 0, 0, 0);
    acc[0][3] = __builtin_amdgcn_mfma_f32_16x16x32_bf16(af0, bf3, acc[0][3], 0, 0, 0);
    acc[1][0] = __builtin_amdgcn_mfma_f32_16x16x32_bf16(af1, bf0, acc[1][0], 0, 0, 0);
    acc[1][1] = __builtin_amdgcn_mfma_f32_16x16x32_bf16(af1, bf1, acc[1][1], 0, 0, 0);
    acc[1][2] = __builtin_amdgcn_mfma_f32_16x16x32_bf16(af1, bf2, acc[1][2], 0, 0, 0);
    acc[1][3] = __builtin_amdgcn_mfma_f32_16x16x32_bf16(af1, bf3, acc[1][3], 0, 0, 0);
    __syncthreads();
  }
  int rbase = (lane >> 4) << 2;
#pragma unroll
  for (int mt = 0; mt < 2; ++mt)
#pragma unroll
    for (int nt = 0; nt < 4; ++nt) {
      int n = n0 + (nt << 4) + mr;
      float bv = bias[n];
#pragma unroll
      for (int r = 0; r < 4; ++r) {
        int mlog = (int)m0 + (wid << 5) + (mt << 4) + rbase + r;
        float val = acc[mt][nt][r] + bv;
        if (CPERM) {
          int b = mlog & 63, tt = mlog >> 6;
          int u = n & 511, g = n >> 9;
          C[((((size_t)tt * 512 + u) * 64 + b) << 2) + g] = f2b(val);
        } else {
          C[(size_t)mlog * N + n] = f2b(val);
        }
      }
    }
}

// ---------------- zero flags ------------------------------------------------------
__global__ void k_zero(u32* __restrict__ p, int n32) {
  int id = blockIdx.x * 256 + threadIdx.x;
  for (int i = id; i < n32; i += gridDim.x * 256) p[i] = 0u;
}

// ---------------- pipelined dual-layer LSTM scan ------------------------------------
// 32 WGs. blocks 0..15 = group0 (layer l0, r4-proven protocol, quad-buffered h0).
// blocks 16..31 = group1 (layer l1): consumes h0[t] (lag 1), computes
//   z1 = rs_b*(Wg1^T h0) - rs_b*m_b*p + q + U1^T h1[t-1]   (LN folded)
// and materializes mid = LN(h0) + h1seq off the critical path.
// Backpressure: group0 step t waits g1 >= t-3 (quad buffer). Deadlock-free:
// group1 strictly trails group0; both windows overlap by construction.
__launch_bounds__(256, 1)
__global__ void k_scan2(const u16* __restrict__ xw2,   // [t][u][b][g] bf16 (layer l0)
                        const u16* __restrict__ Ut0,   // l0 U^T [n][k]
                        const u16* __restrict__ Wg1,   // l1 (W*gamma0)^T [n][k]
                        const u16* __restrict__ Ut1,   // l1 U^T [n][k]
                        const float* __restrict__ p1,  // [2048]
                        const float* __restrict__ q1,  // [2048]
                        const float* __restrict__ g0v, // LN gamma of l0 [512]
                        const float* __restrict__ be0v,// LN beta of l0 [512]
                        u16* __restrict__ hn0,         // quad 4 x [64][512] bf16
                        u16* __restrict__ hn1,         // ping-pong 2 x [64][512] bf16
                        u16* __restrict__ h1seq,       // [t][b][u] bf16
                        u16* __restrict__ mid,         // [t*64+b][u] bf16 = LN(h0)
                        u32* __restrict__ bar) {       // g0 flags @0, g1 flags @2048
  __shared__ u16 hl0[32768];
  __shared__ u16 hl1[32768];
  __shared__ u16 hout[2048];
  __shared__ float stats[128];   // [64 b][2] = m, rs
  int tid = threadIdx.x;
  int lane = tid & 63, wid = tid >> 6;
  int mr = lane & 15, cg = lane >> 4;
  int gate = mr & 3, du = mr >> 2;

  if (blockIdx.x < 16) {
    // ================= GROUP 0 : layer l0 (r4 protocol + quad buffer) ==============
    int w = blockIdx.x;
    int u0 = (w << 5) + (wid << 3);
    short8 af[2][16];
#pragma unroll
    for (int mt = 0; mt < 2; ++mt) {
      size_t urow = (size_t)(gate * Usz + u0 + (mt << 2) + du) * Usz;
#pragma unroll
      for (int kk = 0; kk < 16; ++kk)
        af[mt][kk] = *(const short8*)(Ut0 + urow + (kk << 5) + (cg << 3));
    }
    float cst[2][4];
#pragma unroll
    for (int mt = 0; mt < 2; ++mt)
#pragma unroll
      for (int nt = 0; nt < 4; ++nt) cst[mt][nt] = 0.f;

    short4v xwc[2][4], xwn[2][4];
#pragma unroll
    for (int mt = 0; mt < 2; ++mt)
#pragma unroll
      for (int nt = 0; nt < 4; ++nt)
        xwc[mt][nt] = *(const short4v*)(xw2 + ((((size_t)0 * 512 + u0 + (mt << 2) + cg) * 64
                                               + (nt << 4) + mr) << 2));

    for (int t = 0; t < Tsz; ++t) {
      float4v acc[2][4];
#pragma unroll
      for (int mt = 0; mt < 2; ++mt)
#pragma unroll
        for (int nt = 0; nt < 4; ++nt)
          acc[mt][nt] = (float4v){b2f((u16)xwc[mt][nt][0]), b2f((u16)xwc[mt][nt][1]),
                                  b2f((u16)xwc[mt][nt][2]), b2f((u16)xwc[mt][nt][3])};
      if (t + 1 < Tsz) {
#pragma unroll
        for (int mt = 0; mt < 2; ++mt)
#pragma unroll
          for (int nt = 0; nt < 4; ++nt)
            xwn[mt][nt] = *(const short4v*)(xw2 + ((((size_t)(t + 1) * 512 + u0 + (mt << 2) + cg) * 64
                                                   + (nt << 4) + mr) << 2));
      }

      if (t > 0) {
        if (wid == 0) {
          for (;;) {
            int pass = 1;
            if (lane < 16) {
              u32 v = __hip_atomic_load(bar + lane * FLSTR, __ATOMIC_RELAXED, __HIP_MEMORY_SCOPE_AGENT);
              pass = (v >= (u32)t);
            } else if (lane < 32 && t >= 4) {
              u32 v = __hip_atomic_load(bar + 2048 + (lane - 16) * FLSTR, __ATOMIC_RELAXED, __HIP_MEMORY_SCOPE_AGENT);
              pass = (v >= (u32)(t - 3));
            }
            if (__all(pass)) break;
            __builtin_amdgcn_s_sleep(1);
          }
          __threadfence();
        }
        __syncthreads();

        {
          const char* hsrc = (const char*)(hn0 + (size_t)((t - 1) & 3) * 32768);
#pragma unroll
          for (int j = 0; j < 16; ++j) {
            int c = (wid << 4) + j;
            const char* src = hsrc + ((((c & 3) << 4) + mr) << 10) + ((c >> 2) << 6) + (cg << 4);
            __builtin_amdgcn_global_load_lds(
                (const __attribute__((address_space(1))) void*)src,
                (__attribute__((address_space(3))) void*)(hl0 + (c << 9)),
                16, 0, 0);
          }
        }
        __syncthreads();

#pragma unroll
        for (int kk = 0; kk < 16; ++kk) {
          short8 bfr[4];
#pragma unroll
          for (int nt = 0; nt < 4; ++nt)
            bfr[nt] = *(const short8*)(hl0 + ((((kk << 2) + nt) << 9) + (lane << 3)));
#pragma unroll
          for (int mt = 0; mt < 2; ++mt)
#pragma unroll
            for (int nt = 0; nt < 4; ++nt)
              acc[mt][nt] = __builtin_amdgcn_mfma_f32_16x16x32_bf16(af[mt][kk], bfr[nt], acc[mt][nt], 0, 0, 0);
        }
      }

      u16 hb[2][4];
#pragma unroll
      for (int mt = 0; mt < 2; ++mt)
#pragma unroll
        for (int nt = 0; nt < 4; ++nt) {
          float zi = acc[mt][nt][0], zf = acc[mt][nt][1];
          float zg = acc[mt][nt][2], zo = acc[mt][nt][3];
          float c = sigm(zf) * cst[mt][nt] + sigm(zi) * tanhfast(zg);
          cst[mt][nt] = c;
          hb[mt][nt] = f2b(sigm(zo) * tanhfast(c));
        }

#pragma unroll
      for (int mt = 0; mt < 2; ++mt)
#pragma unroll
        for (int nt = 0; nt < 4; ++nt) {
          int b = (nt << 4) + mr;
          int ul = (wid << 3) + (mt << 2) + cg;
          *(u16*)((char*)hout + (b << 6) + ((ul << 1) ^ ((b & 7) << 3))) = hb[mt][nt];
        }
      __syncthreads();

      {
        int b = tid >> 2, q = tid & 3, s = (b & 7) << 3;
        const char* hrow = (const char*)hout + (b << 6);
        uint2v A0 = *(const uint2v*)(hrow + (((q << 4) | 0) ^ s));
        uint2v A1 = *(const uint2v*)(hrow + (((q << 4) | 8) ^ s));
        uint4v val; val[0] = A0[0]; val[1] = A0[1]; val[2] = A1[0]; val[3] = A1[1];
        *(uint4v*)((char*)(hn0 + (size_t)(t & 3) * 32768) + (b << 10) + (w << 6) + (q << 4)) = val;
      }
      __syncthreads();   // stores drained (vmcnt0 before s_barrier)

      if (tid == 0)
        __hip_atomic_store(bar + w * FLSTR, (u32)(t + 1), __ATOMIC_RELEASE, __HIP_MEMORY_SCOPE_AGENT);

      if (t + 1 < Tsz) {
#pragma unroll
        for (int mt = 0; mt < 2; ++mt)
#pragma unroll
          for (int nt = 0; nt < 4; ++nt) xwc[mt][nt] = xwn[mt][nt];
      }
    }
  } else {
    // ================= GROUP 1 : layer l1 (fused W-proj + LN + recurrence) =========
    int w = blockIdx.x - 16;
    int u0 = (w << 5) + (wid << 3);
    short8 afw[2][16], afu[2][16];
#pragma unroll
    for (int mt = 0; mt < 2; ++mt) {
      size_t urow = (size_t)(gate * Usz + u0 + (mt << 2) + du) * Usz;
#pragma unroll
      for (int kk = 0; kk < 16; ++kk) {
        afw[mt][kk] = *(const short8*)(Wg1 + urow + (kk << 5) + (cg << 3));
        afu[mt][kk] = *(const short8*)(Ut1 + urow + (kk << 5) + (cg << 3));
      }
    }
    float pv[2][4], qv[2][4];
#pragma unroll
    for (int mt = 0; mt < 2; ++mt)
#pragma unroll
      for (int r = 0; r < 4; ++r) {
        int n = r * 512 + u0 + (mt << 2) + cg;
        pv[mt][r] = p1[n]; qv[mt][r] = q1[n];
      }
    // LN params for mid materialization: units w*32 + cg*8 .. +8
    float gv[8], bev[8];
#pragma unroll
    for (int j = 0; j < 8; ++j) {
      gv[j] = g0v[(w << 5) + (cg << 3) + j];
      bev[j] = be0v[(w << 5) + (cg << 3) + j];
    }
    float cst[2][4];
#pragma unroll
    for (int mt = 0; mt < 2; ++mt)
#pragma unroll
      for (int nt = 0; nt < 4; ++nt) cst[mt][nt] = 0.f;

    for (int t = 0; t < Tsz; ++t) {
      // ---- poll: h0[t] ready (g0 >= t+1) and own h1[t-1] ready (g1 >= t) ----
      if (wid == 0) {
        for (;;) {
          int pass = 1;
          if (lane < 16) {
            u32 v = __hip_atomic_load(bar + lane * FLSTR, __ATOMIC_RELAXED, __HIP_MEMORY_SCOPE_AGENT);
            pass = (v >= (u32)(t + 1));
          } else if (lane < 32 && t > 0) {
            u32 v = __hip_atomic_load(bar + 2048 + (lane - 16) * FLSTR, __ATOMIC_RELAXED, __HIP_MEMORY_SCOPE_AGENT);
            pass = (v >= (u32)t);
          }
          if (__all(pass)) break;
          __builtin_amdgcn_s_sleep(1);
        }
        __threadfence();
      }
      __syncthreads();

      // ---- stage h0[t] and h1[t-1] ----
      {
        const char* hsrc = (const char*)(hn0 + (size_t)(t & 3) * 32768);
#pragma unroll
        for (int j = 0; j < 16; ++j) {
          int c = (wid << 4) + j;
          const char* src = hsrc + ((((c & 3) << 4) + mr) << 10) + ((c >> 2) << 6) + (cg << 4);
          __builtin_amdgcn_global_load_lds(
              (const __attribute__((address_space(1))) void*)src,
              (__attribute__((address_space(3))) void*)(hl0 + (c << 9)),
              16, 0, 0);
        }
      }
      if (t > 0) {
        const char* hsrc = (const char*)(hn1 + (size_t)((t - 1) & 1) * 32768);
#pragma unroll
        for (int j = 0; j < 16; ++j) {
          int c = (wid << 4) + j;
          const char* src = hsrc + ((((c & 3) << 4) + mr) << 10) + ((c >> 2) << 6) + (cg << 4);
          __builtin_amdgcn_global_load_lds(
              (const __attribute__((address_space(1))) void*)src,
              (__attribute__((address_space(3))) void*)(hl1 + (c << 9)),
              16, 0, 0);
        }
      }
      __syncthreads();

      // ---- LN stats: wave `wid` handles batch group `wid` ----
      {
        float s = 0.f, sq = 0.f;
#pragma unroll
        for (int kk = 0; kk < 16; ++kk) {
          short8 hv = *(const short8*)(hl0 + ((((kk << 2) + wid) << 9) + (lane << 3)));
#pragma unroll
          for (int j = 0; j < 8; ++j) { float x = b2f((u16)hv[j]); s += x; sq += x * x; }
        }
        s += __shfl_xor(s, 16); s += __shfl_xor(s, 32);
        sq += __shfl_xor(sq, 16); sq += __shfl_xor(sq, 32);
        float m = s * (1.f / 512.f);
        float var = sq * (1.f / 512.f) - m * m;
        float rs = rsqrtf(var + 1e-3f);
        if (lane < 16) { stats[((wid << 4) + lane) * 2] = m; stats[((wid << 4) + lane) * 2 + 1] = rs; }
      }

      // ---- MFMA: accW over h0 (raw), accU over h1[t-1] ----
      float4v aW[2][4], aU[2][4];
#pragma unroll
      for (int mt = 0; mt < 2; ++mt)
#pragma unroll
        for (int nt = 0; nt < 4; ++nt) { aW[mt][nt] = (float4v){0.f,0.f,0.f,0.f}; aU[mt][nt] = (float4v){0.f,0.f,0.f,0.f}; }
#pragma unroll
      for (int kk = 0; kk < 16; ++kk) {
        short8 bfr[4];
#pragma unroll
        for (int nt = 0; nt < 4; ++nt)
          bfr[nt] = *(const short8*)(hl0 + ((((kk << 2) + nt) << 9) + (lane << 3)));
#pragma unroll
        for (int mt = 0; mt < 2; ++mt)
#pragma unroll
          for (int nt = 0; nt < 4; ++nt)
            aW[mt][nt] = __builtin_amdgcn_mfma_f32_16x16x32_bf16(afw[mt][kk], bfr[nt], aW[mt][nt], 0, 0, 0);
      }
      if (t > 0) {
#pragma unroll
        for (int kk = 0; kk < 16; ++kk) {
          short8 bfr[4];
#pragma unroll
          for (int nt = 0; nt < 4; ++nt)
            bfr[nt] = *(const short8*)(hl1 + ((((kk << 2) + nt) << 9) + (lane << 3)));
#pragma unroll
          for (int mt = 0; mt < 2; ++mt)
#pragma unroll
            for (int nt = 0; nt < 4; ++nt)
              aU[mt][nt] = __builtin_amdgcn_mfma_f32_16x16x32_bf16(afu[mt][kk], bfr[nt], aU[mt][nt], 0, 0, 0);
        }
      }
      __syncthreads();   // stats table complete (all waves wrote before MFMA)

      float2v mrs[4];
#pragma unroll
      for (int nt = 0; nt < 4; ++nt)
        mrs[nt] = *(const float2v*)&stats[((nt << 4) + mr) * 2];

      // ---- z = rs*(aW - m*p) + q + aU ; gates ----
      u16 hb[2][4];
#pragma unroll
      for (int mt = 0; mt < 2; ++mt)
#pragma unroll
        for (int nt = 0; nt < 4; ++nt) {
          float m = mrs[nt][0], rs = mrs[nt][1];
          float z0 = rs * (aW[mt][nt][0] - m * pv[mt][0]) + qv[mt][0] + aU[mt][nt][0];
          float z1 = rs * (aW[mt][nt][1] - m * pv[mt][1]) + qv[mt][1] + aU[mt][nt][1];
          float z2 = rs * (aW[mt][nt][2] - m * pv[mt][2]) + qv[mt][2] + aU[mt][nt][2];
          float z3 = rs * (aW[mt][nt][3] - m * pv[mt][3]) + qv[mt][3] + aU[mt][nt][3];
          float c = sigm(z1) * cst[mt][nt] + sigm(z0) * tanhfast(z2);
          cst[mt][nt] = c;
          hb[mt][nt] = f2b(sigm(z3) * tanhfast(c));
        }

#pragma unroll
      for (int mt = 0; mt < 2; ++mt)
#pragma unroll
        for (int nt = 0; nt < 4; ++nt) {
          int b = (nt << 4) + mr;
          int ul = (wid << 3) + (mt << 2) + cg;
          *(u16*)((char*)hout + (b << 6) + ((ul << 1) ^ ((b & 7) << 3))) = hb[mt][nt];
        }
      __syncthreads();

      uint4v val;
      {
        int b = tid >> 2, q = tid & 3, s = (b & 7) << 3;
        const char* hrow = (const char*)hout + (b << 6);
        uint2v A0 = *(const uint2v*)(hrow + (((q << 4) | 0) ^ s));
        uint2v A1 = *(const uint2v*)(hrow + (((q << 4) | 8) ^ s));
        val[0] = A0[0]; val[1] = A0[1]; val[2] = A1[0]; val[3] = A1[1];
        *(uint4v*)((char*)(hn1 + (size_t)(t & 1) * 32768) + (b << 10) + (w << 6) + (q << 4)) = val;
      }
      __syncthreads();   // hn1 stores drained

      if (tid == 0)
        __hip_atomic_store(bar + 2048 + w * FLSTR, (u32)(t + 1), __ATOMIC_RELEASE, __HIP_MEMORY_SCOPE_AGENT);

      // ---- off critical path: h1seq + mid = LN(h0[t]) ----
      {
        int b = tid >> 2, q = tid & 3;
        *(uint4v*)((char*)h1seq + ((size_t)t << 16) + (b << 10) + (w << 6) + (q << 4)) = val;
      }
#pragma unroll
      for (int nt = 0; nt < 4; ++nt) {
        short8 hv = *(const short8*)(hl0 + ((((w << 2) + nt) << 9) + (lane << 3)));
        float m = mrs[nt][0], rs = mrs[nt][1];
        short8 o8;
#pragma unroll
        for (int j = 0; j < 8; ++j)
          o8[j] = (short)f2b((b2f((u16)hv[j]) - m) * rs * gv[j] + bev[j]);
        int b = (nt << 4) + mr;
        *(short8*)(mid + ((size_t)t * 64 + b) * Usz + (w << 5) + (cg << 3)) = o8;
      }
    }
  }
}

// ---------------- LayerNorm + highway fused; rows [t][b] -> out rows [b][t] --------
__launch_bounds__(256)
__global__ void k_lnhw(const u16* __restrict__ hs, const float* __restrict__ g,
                       const float* __restrict__ be, const u16* __restrict__ txr,
                       const u16* __restrict__ ob, float* __restrict__ dout,
                       int dcol, u16* __restrict__ bin) {
  int lane = threadIdx.x & 63, wid = threadIdx.x >> 6;
  size_t row = (size_t)blockIdx.x * 4 + wid;       // physical row = t*64 + b
  short8 v = *(const short8*)(hs + row * Usz + (lane << 3));
  float f[8];
  float s = 0.f, q = 0.f;
#pragma unroll
  for (int j = 0; j < 8; ++j) { f[j] = b2f((u16)v[j]); s += f[j]; q += f[j] * f[j]; }
#pragma unroll
  for (int o = 32; o > 0; o >>= 1) { s += __shfl_xor(s, o); q += __shfl_xor(q, o); }
  float mean = s * (1.f / 512.f);
  float var = q * (1.f / 512.f) - mean * mean;
  float rs = rsqrtf(var + 1e-3f);
  float4v g0 = *(const float4v*)(g + (lane << 3));
  float4v g1 = *(const float4v*)(g + (lane << 3) + 4);
  float4v e0 = *(const float4v*)(be + (lane << 3));
  float4v e1 = *(const float4v*)(be + (lane << 3) + 4);
  short8 tv = *(const short8*)(txr + row * Usz + (lane << 3));
  short8 ov = *(const short8*)(ob + row * Usz + (lane << 3));
  float hwv[8];
#pragma unroll
  for (int j = 0; j < 8; ++j) {
    float gg = (j < 4) ? g0[j] : g1[j - 4];
    float ee = (j < 4) ? e0[j] : e1[j - 4];
    float hx = (f[j] - mean) * rs * gg + ee;
    float tx = sigm(b2f((u16)tv[j]));
    float o_ = b2f((u16)ov[j]);
    hwv[j] = hx * tx + (1.f - tx) * o_;
  }
  size_t orow = ((row & 63) << 9) + (row >> 6);    // b*512 + t
  float4v w0 = {hwv[0], hwv[1], hwv[2], hwv[3]};
  float4v w1 = {hwv[4], hwv[5], hwv[6], hwv[7]};
  *(float4v*)(dout + orow * OUTW + dcol + (lane << 3)) = w0;
  *(float4v*)(dout + orow * OUTW + dcol + (lane << 3) + 4) = w1;
  if (bin) {
    short8 hb;
#pragma unroll
    for (int j = 0; j < 8; ++j) hb[j] = (short)f2b(hwv[j]);
    *(short8*)(bin + orow * BINW + 128 + (lane << 3)) = hb;
  }
}

// ====================================================================================
extern "C" void kernel_launch(void* const* d_in, const int* in_sizes, int n_in,
                              void* d_out, int out_size, void* d_ws, size_t ws_size,
                              hipStream_t stream) {
  (void)in_sizes; (void)n_in; (void)out_size; (void)ws_size;
  const float* x = (const float*)d_in[0];
  const float* W[4]  = {(const float*)d_in[1],  (const float*)d_in[6],
                        (const float*)d_in[11], (const float*)d_in[16]};
  const float* U[4]  = {(const float*)d_in[2],  (const float*)d_in[7],
                        (const float*)d_in[12], (const float*)d_in[17]};
  const float* bb_[4] = {(const float*)d_in[3],  (const float*)d_in[8],
                        (const float*)d_in[13], (const float*)d_in[18]};
  const float* gg_[4] = {(const float*)d_in[4],  (const float*)d_in[9],
                        (const float*)d_in[14], (const float*)d_in[19]};
  const float* be_[4] = {(const float*)d_in[5],  (const float*)d_in[10],
                        (const float*)d_in[15], (const float*)d_in[20]};
  const float* Wtr[2] = {(const float*)d_in[21], (const float*)d_in[23]};
  const float* btr[2] = {(const float*)d_in[22], (const float*)d_in[24]};

  char* ws = (char*)d_ws;
  size_t off = 0;
  u16* xwb   = (u16*)(ws + off); off += (size_t)Msz * Gsz * 2;
  u16* h1seq = (u16*)(ws + off); off += (size_t)Msz * Usz * 2;  // [t][b][u]
  u16* mid   = (u16*)(ws + off); off += (size_t)Msz * Usz * 2;  // [t*64+b][u]
  u16* bin   = (u16*)(ws + off); off += (size_t)Msz * BINW * 2; // [b][t][640]
  const int KIN[4] = {128, 512, 640, 512};
  u16* Wtb[4];
  for (int i = 0; i < 4; ++i) { Wtb[i] = (u16*)(ws + off); off += (size_t)Gsz * KIN[i] * 2; }
  u16* Utb[4];
  for (int i = 0; i < 4; ++i) { Utb[i] = (u16*)(ws + off); off += (size_t)Gsz * Usz * 2; }
  u16* Wtrb[2];
  for (int i = 0; i < 2; ++i) { Wtrb[i] = (u16*)(ws + off); off += (size_t)Usz * Usz * 2; }
  float* pq = (float*)(ws + off); off += 4 * Gsz * 4;           // p0,q0,p1,q1
  u16* hn0 = (u16*)(ws + off); off += 4 * (size_t)Bsz * Usz * 2; // quad
  u16* hn1 = (u16*)(ws + off); off += 2 * (size_t)Bsz * Usz * 2; // ping-pong
  u32* bar = (u32*)(ws + off); off += 16384;                     // 4096 u32
  float* dout = (float*)d_out;

  // weight prep (Wtb[1], Wtb[3] gamma-folded)
  k_wt<<<dim3(Gsz / 32, KIN[0] / 32), 256, 0, stream>>>(W[0], Wtb[0], KIN[0], Gsz, nullptr);
  k_wt<<<dim3(Gsz / 32, KIN[1] / 32), 256, 0, stream>>>(W[1], Wtb[1], KIN[1], Gsz, gg_[0]);
  k_wt<<<dim3(Gsz / 32, KIN[2] / 32), 256, 0, stream>>>(W[2], Wtb[2], KIN[2], Gsz, nullptr);
  k_wt<<<dim3(Gsz / 32, KIN[3] / 32), 256, 0, stream>>>(W[3], Wtb[3], KIN[3], Gsz, gg_[2]);
  for (int i = 0; i < 4; ++i)
    k_wt<<<dim3(Gsz / 32, Usz / 32), 256, 0, stream>>>(U[i], Utb[i], Usz, Gsz, nullptr);
  for (int i = 0; i < 2; ++i)
    k_wt<<<dim3(Usz / 32, Usz / 32), 256, 0, stream>>>(Wtr[i], Wtrb[i], Usz, Usz, nullptr);
  k_pq<<<8, 256, 0, stream>>>(W[1], gg_[0], be_[0], bb_[1], pq + 0 * Gsz, pq + 1 * Gsz);
  k_pq<<<8, 256, 0, stream>>>(W[3], gg_[2], be_[2], bb_[3], pq + 2 * Gsz, pq + 3 * Gsz);

  k_cvx<<<(Msz * 32) / 256, 256, 0, stream>>>(x, dout, bin);

  for (int blk = 0; blk < 2; ++blk) {
    int l0 = blk * 2, l1 = blk * 2 + 1;
    // xw GEMM for layer l0 only (A from bin [b][t], C -> xw2 layout)
    k_gemm<1, 1><<<dim3(Gsz / 64, Msz / 128), 256, 0, stream>>>(bin, BINW, Wtb[l0], KIN[l0], Gsz, bb_[l0], xwb);
    k_zero<<<1, 256, 0, stream>>>(bar, 4096);
    // pipelined dual-layer scan
    k_scan2<<<32, 256, 0, stream>>>(xwb, Utb[l0], Wtb[l1], Utb[l1],
                                    pq + (blk * 2 + 0) * Gsz, pq + (blk * 2 + 1) * Gsz,
                                    gg_[l0], be_[l0], hn0, hn1, h1seq, mid, bar);
    // highway transform gate: Tx_raw = mid @ Wtr + btr (rows [t*64+b])
    k_gemm<0, 0><<<dim3(Usz / 64, Msz / 128), 256, 0, stream>>>(mid, Usz, Wtrb[blk], Usz, Usz, btr[blk], xwb);
    // LN + highway: fp32 out slice (+ bf16 into bin for block-1 input)
    k_lnhw<<<Msz / 4, 256, 0, stream>>>(h1seq, gg_[l1], be_[l1], xwb, mid, dout,
                                        blk == 0 ? 128 : 640, blk == 0 ? bin : (u16*)nullptr);
  }
}